// Round 1
// baseline (1802.757 us; speedup 1.0000x reference)
//
#include <hip/hip_runtime.h>
#include <cstdint>
#include <cstddef>

constexpr int NF = 100000;
constexpr int NA = 400;
constexpr int NC = 30;
constexpr int NN = NF + NA + NC;     // 100430
constexpr int D  = 256;
constexpr int DD = D * D;            // 65536
constexpr int E  = 250000;

// ---------------- per-type encoders: h = relu(x @ W + b) ----------------
template<int K, int ROWS>
__global__ __launch_bounds__(256) void encode_kernel(
    const float* __restrict__ x, const float* __restrict__ W,
    const float* __restrict__ b, float* __restrict__ h,
    int rows, int row_off)
{
    int c = threadIdx.x;
    int base = blockIdx.x * ROWS;
    float wcol[K];
    #pragma unroll
    for (int k = 0; k < K; ++k) wcol[k] = W[k * D + c];
    float bias = b[c];
    for (int i = 0; i < ROWS; ++i) {
        int row = base + i;
        if (row >= rows) return;
        const float* xr = x + (size_t)row * K;
        float acc = bias;
        #pragma unroll
        for (int k = 0; k < K; ++k) acc += xr[k] * wcol[k];
        h[(size_t)(row_off + row) * D + c] = fmaxf(acc, 0.f);
    }
}

// ---------------- degree count ----------------
__global__ __launch_bounds__(256) void deg_count_kernel(
    const int* __restrict__ dst0, const int* __restrict__ dst1,
    const int* __restrict__ dst2, const int* __restrict__ dst3,
    int* __restrict__ deg0, int* __restrict__ deg1,
    int* __restrict__ deg2, int* __restrict__ deg3)
{
    int idx = blockIdx.x * 256 + threadIdx.x;
    if (idx >= 4 * E) return;
    int r = idx / E;
    int e = idx - r * E;
    const int* dst = (r == 0) ? dst0 : (r == 1) ? dst1 : (r == 2) ? dst2 : dst3;
    int* deg       = (r == 0) ? deg0 : (r == 1) ? deg1 : (r == 2) ? deg2 : deg3;
    atomicAdd(&deg[dst[e]], 1);
}

// ---------------- scan stage A: per-chunk sums for the two big relations ----
__global__ __launch_bounds__(1024) void scanA_kernel(
    const int* __restrict__ deg1, const int* __restrict__ deg3, int* __restrict__ bsum)
{
    __shared__ int s[1024];
    int b = blockIdx.x;                    // 0..195
    bool isR3 = (b >= 98);
    const int* deg = isR3 ? deg3 : deg1;
    int chunk = isR3 ? b - 98 : b;
    int i = chunk * 1024 + threadIdx.x;
    int v = (i < NF) ? deg[i] : 0;
    s[threadIdx.x] = v;
    __syncthreads();
    for (int ofs = 512; ofs > 0; ofs >>= 1) {
        if ((int)threadIdx.x < ofs) s[threadIdx.x] += s[threadIdx.x + ofs];
        __syncthreads();
    }
    if (threadIdx.x == 0) bsum[(isR3 ? 128 : 0) + chunk] = s[0];
}

// ---------------- scan stage B: exclusive-scan the partial sums -------------
__global__ __launch_bounds__(256) void scanB_kernel(int* __restrict__ bsum)
{
    __shared__ int s[256];
    int t = threadIdx.x;
    int v = ((t & 127) < 98) ? bsum[t] : 0;
    s[t] = v;
    __syncthreads();
    for (int ofs = 1; ofs < 128; ofs <<= 1) {
        int a = ((t & 127) >= ofs) ? s[t - ofs] : 0;
        __syncthreads();
        s[t] += a;
        __syncthreads();
    }
    bsum[t] = s[t] - v;   // exclusive (segmented per 128-half)
}

// ---------------- scan stage C: write row_ptr / cursor / inv_deg ------------
__global__ __launch_bounds__(1024) void scanC_kernel(
    const int* __restrict__ deg0, const int* __restrict__ deg1,
    const int* __restrict__ deg2, const int* __restrict__ deg3,
    const int* __restrict__ bsum,
    int* __restrict__ rp0, int* __restrict__ rp1, int* __restrict__ rp2, int* __restrict__ rp3,
    int* __restrict__ cu0, int* __restrict__ cu1, int* __restrict__ cu2, int* __restrict__ cu3,
    float* __restrict__ inv0, float* __restrict__ inv1,
    float* __restrict__ inv2, float* __restrict__ inv3)
{
    __shared__ int s[1024];
    int b = blockIdx.x;                    // 0..197
    const int* deg; int n; int* rp; int* cu; float* inv; int chunk; int prefix;
    if (b < 98)       { deg = deg1; n = NF; rp = rp1; cu = cu1; inv = inv1; chunk = b;      prefix = bsum[chunk]; }
    else if (b < 196) { deg = deg3; n = NF; rp = rp3; cu = cu3; inv = inv3; chunk = b - 98; prefix = bsum[128 + chunk]; }
    else if (b == 196){ deg = deg0; n = NA; rp = rp0; cu = cu0; inv = inv0; chunk = 0;      prefix = 0; }
    else              { deg = deg2; n = NC; rp = rp2; cu = cu2; inv = inv2; chunk = 0;      prefix = 0; }
    int tid = threadIdx.x;
    int i = chunk * 1024 + tid;
    int v = (i < n) ? deg[i] : 0;
    s[tid] = v;
    __syncthreads();
    for (int ofs = 1; ofs < 1024; ofs <<= 1) {
        int a = (tid >= ofs) ? s[tid - ofs] : 0;
        __syncthreads();
        s[tid] += a;
        __syncthreads();
    }
    int ex = prefix + s[tid] - v;
    if (i < n) {
        rp[i] = ex;
        cu[i] = ex;
        inv[i] = 1.0f / (float)(v > 1 ? v : 1);
    }
    if (i == 0) rp[n] = E;
}

// ---------------- CSR fill ----------------
__global__ __launch_bounds__(256) void csr_fill_kernel(
    const int* __restrict__ src0, const int* __restrict__ dst0,
    const int* __restrict__ src1, const int* __restrict__ dst1,
    const int* __restrict__ src2, const int* __restrict__ dst2,
    const int* __restrict__ src3, const int* __restrict__ dst3,
    int* __restrict__ cu0, int* __restrict__ cu1,
    int* __restrict__ cu2, int* __restrict__ cu3,
    int* __restrict__ csr0, int* __restrict__ csr1,
    int* __restrict__ csr2, int* __restrict__ csr3)
{
    int idx = blockIdx.x * 256 + threadIdx.x;
    if (idx >= 4 * E) return;
    int r = idx / E;
    int e = idx - r * E;
    const int* src; const int* dst; int* cu; int* csr;
    if (r == 0)      { src = src0; dst = dst0; cu = cu0; csr = csr0; }
    else if (r == 1) { src = src1; dst = dst1; cu = cu1; csr = csr1; }
    else if (r == 2) { src = src2; dst = dst2; cu = cu2; csr = csr2; }
    else             { src = src3; dst = dst3; cu = cu3; csr = csr3; }
    int dd = dst[e];
    int pos = atomicAdd(&cu[dd], 1);
    csr[pos] = src[e];
}

// ---------------- basis combine: Wr[r] = sum_b comp[r,b] * basis[b] ---------
__global__ __launch_bounds__(256) void wr_kernel(
    const float* __restrict__ basis, const float* __restrict__ comp, float* __restrict__ wr)
{
    int idx = blockIdx.x * 256 + threadIdx.x;   // < 4*DD
    int r = idx >> 16;
    int io = idx & (DD - 1);
    wr[idx] = comp[r * 3 + 0] * basis[io]
            + comp[r * 3 + 1] * basis[DD + io]
            + comp[r * 3 + 2] * basis[2 * DD + io];
}

// ---------------- y = h[src-type rows] @ Wr  (unique sources of r1/r3) ------
__global__ __launch_bounds__(256) void y_kernel(
    const float* __restrict__ h, const float* __restrict__ wr, float* __restrict__ y)
{
    int row = blockIdx.x;            // 0..429  (airports then carriers)
    int c = threadIdx.x;
    const float* src = h + (size_t)(NF + row) * D;
    const float* W = (row < NA) ? (wr + DD) : (wr + 3 * DD);
    float acc = 0.f;
    #pragma unroll 8
    for (int k = 0; k < D; ++k) acc += src[k] * W[k * D + c];
    y[(size_t)row * D + c] = acc;
}

// ---------------- big fp32 GEMM: out = h @ root + bias (all NN rows) --------
__global__ __launch_bounds__(256) void gemm_root(
    const float* __restrict__ A, const float* __restrict__ Bm,
    const float* __restrict__ bias, float* __restrict__ C)
{
    __shared__ float As[32][68];
    __shared__ float Bs[32][68];
    const int row0 = blockIdx.x * 64;
    const int col0 = blockIdx.y * 64;
    const int tid = threadIdx.x;
    const int tx = tid & 15, ty = tid >> 4;
    const int alr = tid >> 2;            // 0..63 A row in tile
    const int alk = (tid & 3) * 8;       // k offset 0,8,16,24
    const int blr = tid >> 3;            // 0..31 B k-row
    const int blc = (tid & 7) * 8;       // col offset
    float acc[4][4] = {};
    int ar = row0 + alr; if (ar >= NN) ar = NN - 1;
    const float* Arow = A + (size_t)ar * D;
    for (int k0 = 0; k0 < D; k0 += 32) {
        float4 a0 = *(const float4*)(Arow + k0 + alk);
        float4 a1 = *(const float4*)(Arow + k0 + alk + 4);
        float4 b0 = *(const float4*)(Bm + (size_t)(k0 + blr) * D + col0 + blc);
        float4 b1 = *(const float4*)(Bm + (size_t)(k0 + blr) * D + col0 + blc + 4);
        __syncthreads();
        As[alk + 0][alr] = a0.x; As[alk + 1][alr] = a0.y;
        As[alk + 2][alr] = a0.z; As[alk + 3][alr] = a0.w;
        As[alk + 4][alr] = a1.x; As[alk + 5][alr] = a1.y;
        As[alk + 6][alr] = a1.z; As[alk + 7][alr] = a1.w;
        *(float4*)(&Bs[blr][blc])     = b0;
        *(float4*)(&Bs[blr][blc + 4]) = b1;
        __syncthreads();
        #pragma unroll
        for (int k = 0; k < 32; ++k) {
            float4 av = *(const float4*)(&As[k][ty * 4]);
            float4 bv = *(const float4*)(&Bs[k][tx * 4]);
            float a[4] = {av.x, av.y, av.z, av.w};
            float b[4] = {bv.x, bv.y, bv.z, bv.w};
            #pragma unroll
            for (int i = 0; i < 4; ++i)
                #pragma unroll
                for (int j = 0; j < 4; ++j)
                    acc[i][j] += a[i] * b[j];
        }
    }
    float4 bv = *(const float4*)(bias + col0 + tx * 4);
    #pragma unroll
    for (int i = 0; i < 4; ++i) {
        int r = row0 + ty * 4 + i;
        if (r < NN) {
            float4 o;
            o.x = acc[i][0] + bv.x; o.y = acc[i][1] + bv.y;
            o.z = acc[i][2] + bv.z; o.w = acc[i][3] + bv.w;
            *(float4*)(C + (size_t)r * D + col0 + tx * 4) = o;
        }
    }
}

// ---------------- r0/r2: agg[dst] += h[src] over CSR chunks -----------------
__global__ __launch_bounds__(256) void agg_small_kernel(
    const float* __restrict__ h,
    const int* __restrict__ rp0, const int* __restrict__ csr0,
    const int* __restrict__ rp2, const int* __restrict__ csr2,
    float* __restrict__ agg)
{
    int b = blockIdx.x;
    const int* rp; const int* csr; int dstn, chunk, nch; float* arow;
    if (b < NA * 4) { dstn = b >> 2; chunk = b & 3; nch = 4;  rp = rp0; csr = csr0; arow = agg + (size_t)dstn * D; }
    else { int bb = b - NA * 4; dstn = bb >> 6; chunk = bb & 63; nch = 64; rp = rp2; csr = csr2; arow = agg + (size_t)(NA + dstn) * D; }
    int s = rp[dstn], e = rp[dstn + 1];
    int cnt = e - s;
    int lo = s + (int)((long long)cnt * chunk / nch);
    int hi = s + (int)((long long)cnt * (chunk + 1) / nch);
    int c = threadIdx.x;
    float acc = 0.f;
    int p = lo;
    for (; p + 3 < hi; p += 4) {
        int s0 = csr[p], s1 = csr[p + 1], s2 = csr[p + 2], s3 = csr[p + 3];
        acc += h[(size_t)s0 * D + c] + h[(size_t)s1 * D + c]
             + h[(size_t)s2 * D + c] + h[(size_t)s3 * D + c];
    }
    for (; p < hi; ++p) acc += h[(size_t)csr[p] * D + c];
    atomicAdd(arow + c, acc);
}

// ------- r0/r2 transform: out[dst] += inv_deg * (agg @ Wr), then relu -------
__global__ __launch_bounds__(256) void smallT_kernel(
    const float* __restrict__ agg, const float* __restrict__ wr,
    const float* __restrict__ inv0, const float* __restrict__ inv2,
    float* __restrict__ outb)
{
    int row = blockIdx.x;            // 0..429
    int c = threadIdx.x;
    const float* a = agg + (size_t)row * D;
    const float* W = (row < NA) ? wr : (wr + 2 * DD);
    float scale = (row < NA) ? inv0[row] : inv2[row - NA];
    float acc = 0.f;
    #pragma unroll 8
    for (int k = 0; k < D; ++k) acc += a[k] * W[k * D + c];
    size_t o = (size_t)(NF + row) * D + c;
    float v = outb[o] + scale * acc;
    outb[o] = fmaxf(v, 0.f);
}

// ------- r1/r3 gather into flights: out[f] += inv*Σ y[src], then relu -------
__global__ __launch_bounds__(256) void r1r3_kernel(
    const float* __restrict__ y,
    const int* __restrict__ rp1, const int* __restrict__ csr1, const float* __restrict__ inv1,
    const int* __restrict__ rp3, const int* __restrict__ csr3, const float* __restrict__ inv3,
    float* __restrict__ outb)
{
    int c = threadIdx.x;
    int base = blockIdx.x * 8;
    for (int i = 0; i < 8; ++i) {
        int f = base + i;
        if (f >= NF) return;
        float s1 = 0.f;
        for (int a = rp1[f]; a < rp1[f + 1]; ++a)
            s1 += y[(size_t)csr1[a] * D + c];
        float s3 = 0.f;
        for (int a = rp3[f]; a < rp3[f + 1]; ++a)
            s3 += y[(size_t)(NA + csr3[a]) * D + c];
        size_t o = (size_t)f * D + c;
        float v = outb[o] + inv1[f] * s1 + inv3[f] * s3;
        outb[o] = fmaxf(v, 0.f);
    }
}

// ---------------- readout: out[f] = h[f] . W_out + b_out --------------------
__global__ __launch_bounds__(256) void readout_kernel(
    const float* __restrict__ h, const float* __restrict__ wout,
    const float* __restrict__ bout, float* __restrict__ out)
{
    int w = threadIdx.x >> 6, lane = threadIdx.x & 63;
    int row = blockIdx.x * 4 + w;
    if (row >= NF) return;
    float4 hv = *(const float4*)(h + (size_t)row * D + lane * 4);
    float4 wv = *(const float4*)(wout + lane * 4);
    float d = hv.x * wv.x + hv.y * wv.y + hv.z * wv.z + hv.w * wv.w;
    #pragma unroll
    for (int s = 32; s > 0; s >>= 1) d += __shfl_down(d, s);
    if (lane == 0) out[row] = d + bout[0];
}

extern "C" void kernel_launch(void* const* d_in, const int* in_sizes, int n_in,
                              void* d_out, int out_size, void* d_ws, size_t ws_size,
                              hipStream_t stream)
{
    const float* xf = (const float*)d_in[0];
    const float* xa = (const float*)d_in[1];
    const float* xc = (const float*)d_in[2];
    const float* Wf = (const float*)d_in[3];
    const float* bf = (const float*)d_in[4];
    const float* Wa = (const float*)d_in[5];
    const float* ba = (const float*)d_in[6];
    const float* Wc = (const float*)d_in[7];
    const float* bc = (const float*)d_in[8];
    const float* basis0 = (const float*)d_in[9];
    const float* comp0  = (const float*)d_in[10];
    const float* root0  = (const float*)d_in[11];
    const float* bias0  = (const float*)d_in[12];
    const float* basis1 = (const float*)d_in[13];
    const float* comp1  = (const float*)d_in[14];
    const float* root1  = (const float*)d_in[15];
    const float* bias1  = (const float*)d_in[16];
    const float* Wout = (const float*)d_in[17];
    const float* bout = (const float*)d_in[18];
    const int* src0 = (const int*)d_in[19];
    const int* dst0 = (const int*)d_in[20];
    const int* src1 = (const int*)d_in[21];
    const int* dst1 = (const int*)d_in[22];
    const int* src2 = (const int*)d_in[23];
    const int* dst2 = (const int*)d_in[24];
    const int* src3 = (const int*)d_in[25];
    const int* dst3 = (const int*)d_in[26];
    float* out = (float*)d_out;

    char* ws = (char*)d_ws;
    size_t off = 0;
    auto alloc = [&](size_t bytes) -> char* {
        char* p = ws + off;
        off = (off + bytes + 255) & ~(size_t)255;
        return p;
    };
    float* hbuf   = (float*)alloc((size_t)NN * D * 4);
    float* obuf   = (float*)alloc((size_t)NN * D * 4);
    float* wrbuf  = (float*)alloc((size_t)4 * DD * 4);
    float* ybuf   = (float*)alloc((size_t)(NA + NC) * D * 4);
    float* aggbuf = (float*)alloc((size_t)(NA + NC) * D * 4);
    int*   deg_all= (int*)  alloc((size_t)(NA + NF + NC + NF) * 4);
    int* deg0 = deg_all; int* deg1 = deg0 + NA; int* deg2 = deg1 + NF; int* deg3 = deg2 + NC;
    float* inv_all= (float*)alloc((size_t)(NA + NF + NC + NF) * 4);
    float* inv0 = inv_all; float* inv1 = inv0 + NA; float* inv2 = inv1 + NF; float* inv3 = inv2 + NC;
    int* rp0 = (int*)alloc((NA + 1) * 4);
    int* rp1 = (int*)alloc((size_t)(NF + 1) * 4);
    int* rp2 = (int*)alloc((NC + 1) * 4);
    int* rp3 = (int*)alloc((size_t)(NF + 1) * 4);
    int* cu0 = (int*)alloc((NA + 1) * 4);
    int* cu1 = (int*)alloc((size_t)(NF + 1) * 4);
    int* cu2 = (int*)alloc((NC + 1) * 4);
    int* cu3 = (int*)alloc((size_t)(NF + 1) * 4);
    int* csr0 = (int*)alloc((size_t)E * 4);
    int* csr1 = (int*)alloc((size_t)E * 4);
    int* csr2 = (int*)alloc((size_t)E * 4);
    int* csr3 = (int*)alloc((size_t)E * 4);
    int* bsum = (int*)alloc(256 * 4);
    (void)ws_size; (void)in_sizes; (void)n_in; (void)out_size;

    // ---- CSR build (edges are static inputs; rebuilt deterministically each call)
    hipMemsetAsync(deg_all, 0, (size_t)(NA + NF + NC + NF) * 4, stream);
    deg_count_kernel<<<(4 * E + 255) / 256, 256, 0, stream>>>(
        dst0, dst1, dst2, dst3, deg0, deg1, deg2, deg3);
    scanA_kernel<<<196, 1024, 0, stream>>>(deg1, deg3, bsum);
    scanB_kernel<<<1, 256, 0, stream>>>(bsum);
    scanC_kernel<<<198, 1024, 0, stream>>>(
        deg0, deg1, deg2, deg3, bsum,
        rp0, rp1, rp2, rp3, cu0, cu1, cu2, cu3,
        inv0, inv1, inv2, inv3);
    csr_fill_kernel<<<(4 * E + 255) / 256, 256, 0, stream>>>(
        src0, dst0, src1, dst1, src2, dst2, src3, dst3,
        cu0, cu1, cu2, cu3, csr0, csr1, csr2, csr3);

    // ---- encoders
    encode_kernel<32, 8><<<NF / 8, 256, 0, stream>>>(xf, Wf, bf, hbuf, NF, 0);
    encode_kernel<16, 8><<<(NA + 7) / 8, 256, 0, stream>>>(xa, Wa, ba, hbuf, NA, NF);
    encode_kernel<8, 8><<<(NC + 7) / 8, 256, 0, stream>>>(xc, Wc, bc, hbuf, NC, NF + NA);

    // ---- RGCN layers
    auto layer = [&](const float* hin, float* hout,
                     const float* basis, const float* comp,
                     const float* root, const float* bias) {
        wr_kernel<<<4 * DD / 256, 256, 0, stream>>>(basis, comp, wrbuf);
        y_kernel<<<NA + NC, 256, 0, stream>>>(hin, wrbuf, ybuf);
        gemm_root<<<dim3((NN + 63) / 64, 4), 256, 0, stream>>>(hin, root, bias, hout);
        hipMemsetAsync(aggbuf, 0, (size_t)(NA + NC) * D * 4, stream);
        agg_small_kernel<<<NA * 4 + NC * 64, 256, 0, stream>>>(
            hin, rp0, csr0, rp2, csr2, aggbuf);
        smallT_kernel<<<NA + NC, 256, 0, stream>>>(aggbuf, wrbuf, inv0, inv2, hout);
        r1r3_kernel<<<NF / 8, 256, 0, stream>>>(
            ybuf, rp1, csr1, inv1, rp3, csr3, inv3, hout);
    };
    layer(hbuf, obuf, basis0, comp0, root0, bias0);
    layer(obuf, hbuf, basis1, comp1, root1, bias1);

    // ---- readout
    readout_kernel<<<NF / 4, 256, 0, stream>>>(hbuf, Wout, bout, out);
}

// Round 2
// 778.820 us; speedup vs baseline: 2.3147x; 2.3147x over previous
//
#include <hip/hip_runtime.h>
#include <cstdint>
#include <cstddef>

constexpr int NF = 100000;
constexpr int NA = 400;
constexpr int NC = 30;
constexpr int NN = NF + NA + NC;     // 100430
constexpr int D  = 256;
constexpr int DD = D * D;            // 65536
constexpr int E  = 250000;
constexpr int NSL = 128;             // slices for r0/r2 counting sort

// ---------------- per-type encoders: h = relu(x @ W + b) ----------------
template<int K, int ROWS>
__global__ __launch_bounds__(256) void encode_kernel(
    const float* __restrict__ x, const float* __restrict__ W,
    const float* __restrict__ b, float* __restrict__ h,
    int rows, int row_off)
{
    int c = threadIdx.x;
    int base = blockIdx.x * ROWS;
    float wcol[K];
    #pragma unroll
    for (int k = 0; k < K; ++k) wcol[k] = W[k * D + c];
    float bias = b[c];
    for (int i = 0; i < ROWS; ++i) {
        int row = base + i;
        if (row >= rows) return;
        const float* xr = x + (size_t)row * K;
        float acc = bias;
        #pragma unroll
        for (int k = 0; k < K; ++k) acc += xr[k] * wcol[k];
        h[(size_t)(row_off + row) * D + c] = fmaxf(acc, 0.f);
    }
}

// ---------------- r1/r3 degree count (low contention: 100K dsts) ----------
__global__ __launch_bounds__(256) void deg_count_kernel(
    const int* __restrict__ dst1, const int* __restrict__ dst3,
    int* __restrict__ deg1, int* __restrict__ deg3)
{
    int idx = blockIdx.x * 256 + threadIdx.x;
    if (idx >= 2 * E) return;
    if (idx < E) atomicAdd(&deg1[dst1[idx]], 1);
    else         atomicAdd(&deg3[dst3[idx - E]], 1);
}

// ---------------- r0/r2: per-slice LDS histograms (contention-free) --------
__global__ __launch_bounds__(256) void hist02_kernel(
    const int* __restrict__ dst0, const int* __restrict__ dst2,
    int* __restrict__ bh0, int* __restrict__ bh2)
{
    __shared__ int hist[NA];
    int b = blockIdx.x;                 // 0..2*NSL-1
    bool isR2 = (b >= NSL);
    int sl = isR2 ? b - NSL : b;
    const int* dst = isR2 ? dst2 : dst0;
    int nb = isR2 ? NC : NA;
    for (int i = threadIdx.x; i < nb; i += 256) hist[i] = 0;
    __syncthreads();
    int lo = (int)((long long)E * sl / NSL);
    int hi = (int)((long long)E * (sl + 1) / NSL);
    for (int e = lo + threadIdx.x; e < hi; e += 256)
        atomicAdd(&hist[dst[e]], 1);
    __syncthreads();
    int* bh = isR2 ? (bh2 + sl * NC) : (bh0 + sl * NA);
    for (int i = threadIdx.x; i < nb; i += 256) bh[i] = hist[i];
}

// -------- scan: per-bin over slices + cross-bin; emits rp/inv + abs offsets -
__global__ __launch_bounds__(512) void scan02_kernel(
    int* __restrict__ bh0, int* __restrict__ bh2,
    int* __restrict__ rp0, int* __restrict__ rp2,
    float* __restrict__ inv0, float* __restrict__ inv2)
{
    __shared__ int tot[512];
    __shared__ int exc[512];
    int t = threadIdx.x;
    int cnt = 0;
    if (t < NA) {
        int s = 0;
        for (int sl = 0; sl < NSL; ++sl) {
            int v = bh0[sl * NA + t]; bh0[sl * NA + t] = s; s += v;
        }
        cnt = s;
    } else if (t < NA + NC) {
        int bin = t - NA; int s = 0;
        for (int sl = 0; sl < NSL; ++sl) {
            int v = bh2[sl * NC + bin]; bh2[sl * NC + bin] = s; s += v;
        }
        cnt = s;
    }
    tot[t] = cnt;
    __syncthreads();
    for (int ofs = 1; ofs < 512; ofs <<= 1) {
        int v = (t >= ofs) ? tot[t - ofs] : 0;
        __syncthreads();
        tot[t] += v;
        __syncthreads();
    }
    int ex = tot[t] - cnt;              // exclusive over combined [r0 | r2]
    if (t < NA) {
        exc[t] = ex;
        rp0[t] = ex;
        inv0[t] = 1.0f / (float)(cnt > 1 ? cnt : 1);
        if (t == 0) { rp0[NA] = E; rp2[NC] = E; }
    } else if (t < NA + NC) {
        exc[t] = ex - E;                // r2 csr buffer is its own array
        rp2[t - NA] = ex - E;
        inv2[t - NA] = 1.0f / (float)(cnt > 1 ? cnt : 1);
    } else exc[t] = 0;
    __syncthreads();
    for (int idx = t; idx < NSL * NA; idx += 512) {
        int sl = idx / NA; int bin = idx - sl * NA;
        bh0[idx] += exc[bin];
    }
    for (int idx = t; idx < NSL * NC; idx += 512) {
        int sl = idx / NC; int bin = idx - sl * NC;
        bh2[idx] += exc[NA + bin];
    }
}

// ---------------- r0/r2 CSR fill with LDS cursors --------------------------
__global__ __launch_bounds__(256) void fill02_kernel(
    const int* __restrict__ src0, const int* __restrict__ dst0,
    const int* __restrict__ src2, const int* __restrict__ dst2,
    const int* __restrict__ bh0, const int* __restrict__ bh2,
    int* __restrict__ csr0, int* __restrict__ csr2)
{
    __shared__ int cur[NA];
    int b = blockIdx.x;
    bool isR2 = (b >= NSL);
    int sl = isR2 ? b - NSL : b;
    const int* src = isR2 ? src2 : src0;
    const int* dst = isR2 ? dst2 : dst0;
    const int* bh  = isR2 ? (bh2 + sl * NC) : (bh0 + sl * NA);
    int* csr       = isR2 ? csr2 : csr0;
    int nb = isR2 ? NC : NA;
    for (int i = threadIdx.x; i < nb; i += 256) cur[i] = bh[i];
    __syncthreads();
    int lo = (int)((long long)E * sl / NSL);
    int hi = (int)((long long)E * (sl + 1) / NSL);
    for (int e = lo + threadIdx.x; e < hi; e += 256) {
        int pos = atomicAdd(&cur[dst[e]], 1);
        csr[pos] = src[e];
    }
}

// ---------------- r1/r3 scan chain (unchanged structure) -------------------
__global__ __launch_bounds__(1024) void scanA_kernel(
    const int* __restrict__ deg1, const int* __restrict__ deg3, int* __restrict__ bsum)
{
    __shared__ int s[1024];
    int b = blockIdx.x;                    // 0..195
    bool isR3 = (b >= 98);
    const int* deg = isR3 ? deg3 : deg1;
    int chunk = isR3 ? b - 98 : b;
    int i = chunk * 1024 + threadIdx.x;
    int v = (i < NF) ? deg[i] : 0;
    s[threadIdx.x] = v;
    __syncthreads();
    for (int ofs = 512; ofs > 0; ofs >>= 1) {
        if ((int)threadIdx.x < ofs) s[threadIdx.x] += s[threadIdx.x + ofs];
        __syncthreads();
    }
    if (threadIdx.x == 0) bsum[(isR3 ? 128 : 0) + chunk] = s[0];
}

__global__ __launch_bounds__(256) void scanB_kernel(int* __restrict__ bsum)
{
    __shared__ int s[256];
    int t = threadIdx.x;
    int v = ((t & 127) < 98) ? bsum[t] : 0;
    s[t] = v;
    __syncthreads();
    for (int ofs = 1; ofs < 128; ofs <<= 1) {
        int a = ((t & 127) >= ofs) ? s[t - ofs] : 0;
        __syncthreads();
        s[t] += a;
        __syncthreads();
    }
    bsum[t] = s[t] - v;   // exclusive (segmented per 128-half)
}

__global__ __launch_bounds__(1024) void scanC_kernel(
    const int* __restrict__ deg1, const int* __restrict__ deg3,
    const int* __restrict__ bsum,
    int* __restrict__ rp1, int* __restrict__ rp3,
    int* __restrict__ cu1, int* __restrict__ cu3,
    float* __restrict__ inv1, float* __restrict__ inv3)
{
    __shared__ int s[1024];
    int b = blockIdx.x;                    // 0..195
    const int* deg; int* rp; int* cu; float* inv; int chunk; int prefix;
    if (b < 98) { deg = deg1; rp = rp1; cu = cu1; inv = inv1; chunk = b;      prefix = bsum[chunk]; }
    else        { deg = deg3; rp = rp3; cu = cu3; inv = inv3; chunk = b - 98; prefix = bsum[128 + chunk]; }
    int tid = threadIdx.x;
    int i = chunk * 1024 + tid;
    int v = (i < NF) ? deg[i] : 0;
    s[tid] = v;
    __syncthreads();
    for (int ofs = 1; ofs < 1024; ofs <<= 1) {
        int a = (tid >= ofs) ? s[tid - ofs] : 0;
        __syncthreads();
        s[tid] += a;
        __syncthreads();
    }
    int ex = prefix + s[tid] - v;
    if (i < NF) {
        rp[i] = ex;
        cu[i] = ex;
        inv[i] = 1.0f / (float)(v > 1 ? v : 1);
    }
    if (i == 0) rp[NF] = E;
}

__global__ __launch_bounds__(256) void csr_fill13_kernel(
    const int* __restrict__ src1, const int* __restrict__ dst1,
    const int* __restrict__ src3, const int* __restrict__ dst3,
    int* __restrict__ cu1, int* __restrict__ cu3,
    int* __restrict__ csr1, int* __restrict__ csr3)
{
    int idx = blockIdx.x * 256 + threadIdx.x;
    if (idx >= 2 * E) return;
    if (idx < E) {
        int pos = atomicAdd(&cu1[dst1[idx]], 1);
        csr1[pos] = src1[idx];
    } else {
        int e = idx - E;
        int pos = atomicAdd(&cu3[dst3[e]], 1);
        csr3[pos] = src3[e];
    }
}

// ---------------- basis combine: Wr[r] = sum_b comp[r,b] * basis[b] ---------
__global__ __launch_bounds__(256) void wr_kernel(
    const float* __restrict__ basis, const float* __restrict__ comp, float* __restrict__ wr)
{
    int idx = blockIdx.x * 256 + threadIdx.x;   // < 4*DD
    int r = idx >> 16;
    int io = idx & (DD - 1);
    wr[idx] = comp[r * 3 + 0] * basis[io]
            + comp[r * 3 + 1] * basis[DD + io]
            + comp[r * 3 + 2] * basis[2 * DD + io];
}

// ---------------- y = h[src-type rows] @ Wr  (unique sources of r1/r3) ------
__global__ __launch_bounds__(256) void y_kernel(
    const float* __restrict__ h, const float* __restrict__ wr, float* __restrict__ y)
{
    int row = blockIdx.x;            // 0..429  (airports then carriers)
    int c = threadIdx.x;
    const float* src = h + (size_t)(NF + row) * D;
    const float* W = (row < NA) ? (wr + DD) : (wr + 3 * DD);
    float acc = 0.f;
    #pragma unroll 8
    for (int k = 0; k < D; ++k) acc += src[k] * W[k * D + c];
    y[(size_t)row * D + c] = acc;
}

// ------- big fp32 GEMM: out = h @ root + bias, 128x128 tile, 8x8/thread -----
__global__ __launch_bounds__(256) void gemm_root(
    const float* __restrict__ A, const float* __restrict__ Bm,
    const float* __restrict__ bias, float* __restrict__ C)
{
    constexpr int BM = 128, BN = 128, BK = 16;
    __shared__ float As[BK][BM + 4];
    __shared__ float Bs[BK][BN + 4];
    const int row0 = blockIdx.x * BM;
    const int col0 = blockIdx.y * BN;
    const int t = threadIdx.x;
    const int tx = t & 15, ty = t >> 4;
    float acc[8][8] = {};
    int arow = t >> 1;                 // 0..127
    int acol = (t & 1) * 8;            // 0 or 8
    int ar = row0 + arow; if (ar >= NN) ar = NN - 1;
    const float* Ap = A + (size_t)ar * D + acol;
    const float* Bp = Bm + (size_t)(t >> 4) * D + col0 + (t & 15) * 8;
    for (int k0 = 0; k0 < D; k0 += BK) {
        float4 a0 = *(const float4*)(Ap + k0);
        float4 a1 = *(const float4*)(Ap + k0 + 4);
        float4 b0 = *(const float4*)(Bp + (size_t)k0 * D);
        float4 b1 = *(const float4*)(Bp + (size_t)k0 * D + 4);
        __syncthreads();
        As[acol + 0][arow] = a0.x; As[acol + 1][arow] = a0.y;
        As[acol + 2][arow] = a0.z; As[acol + 3][arow] = a0.w;
        As[acol + 4][arow] = a1.x; As[acol + 5][arow] = a1.y;
        As[acol + 6][arow] = a1.z; As[acol + 7][arow] = a1.w;
        *(float4*)(&Bs[t >> 4][(t & 15) * 8])     = b0;
        *(float4*)(&Bs[t >> 4][(t & 15) * 8 + 4]) = b1;
        __syncthreads();
        #pragma unroll
        for (int k = 0; k < BK; ++k) {
            float4 x0 = *(const float4*)(&As[k][ty * 4]);
            float4 x1 = *(const float4*)(&As[k][ty * 4 + 64]);
            float4 y0 = *(const float4*)(&Bs[k][tx * 4]);
            float4 y1 = *(const float4*)(&Bs[k][tx * 4 + 64]);
            float a8[8] = {x0.x, x0.y, x0.z, x0.w, x1.x, x1.y, x1.z, x1.w};
            float b8[8] = {y0.x, y0.y, y0.z, y0.w, y1.x, y1.y, y1.z, y1.w};
            #pragma unroll
            for (int i = 0; i < 8; ++i)
                #pragma unroll
                for (int j = 0; j < 8; ++j)
                    acc[i][j] += a8[i] * b8[j];
        }
    }
    float4 bv0 = *(const float4*)(bias + col0 + tx * 4);
    float4 bv1 = *(const float4*)(bias + col0 + tx * 4 + 64);
    float bb[8] = {bv0.x, bv0.y, bv0.z, bv0.w, bv1.x, bv1.y, bv1.z, bv1.w};
    #pragma unroll
    for (int i = 0; i < 8; ++i) {
        int r = row0 + ty * 4 + (i & 3) + ((i >= 4) ? 64 : 0);
        if (r < NN) {
            float* Cp = C + (size_t)r * D + col0 + tx * 4;
            float4 o0, o1;
            o0.x = acc[i][0] + bb[0]; o0.y = acc[i][1] + bb[1];
            o0.z = acc[i][2] + bb[2]; o0.w = acc[i][3] + bb[3];
            o1.x = acc[i][4] + bb[4]; o1.y = acc[i][5] + bb[5];
            o1.z = acc[i][6] + bb[6]; o1.w = acc[i][7] + bb[7];
            *(float4*)Cp = o0;
            *(float4*)(Cp + 64) = o1;
        }
    }
}

// ---------------- r0/r2: agg[dst] += h[src] over CSR chunks -----------------
__global__ __launch_bounds__(256) void agg_small_kernel(
    const float* __restrict__ h,
    const int* __restrict__ rp0, const int* __restrict__ csr0,
    const int* __restrict__ rp2, const int* __restrict__ csr2,
    float* __restrict__ agg)
{
    int b = blockIdx.x;
    const int* rp; const int* csr; int dstn, chunk, nch; float* arow;
    if (b < NA * 4) { dstn = b >> 2; chunk = b & 3; nch = 4;  rp = rp0; csr = csr0; arow = agg + (size_t)dstn * D; }
    else { int bb = b - NA * 4; dstn = bb >> 6; chunk = bb & 63; nch = 64; rp = rp2; csr = csr2; arow = agg + (size_t)(NA + dstn) * D; }
    int s = rp[dstn], e = rp[dstn + 1];
    int cnt = e - s;
    int lo = s + (int)((long long)cnt * chunk / nch);
    int hi = s + (int)((long long)cnt * (chunk + 1) / nch);
    int c = threadIdx.x;
    float acc = 0.f;
    int p = lo;
    for (; p + 3 < hi; p += 4) {
        int s0 = csr[p], s1 = csr[p + 1], s2 = csr[p + 2], s3 = csr[p + 3];
        acc += h[(size_t)s0 * D + c] + h[(size_t)s1 * D + c]
             + h[(size_t)s2 * D + c] + h[(size_t)s3 * D + c];
    }
    for (; p < hi; ++p) acc += h[(size_t)csr[p] * D + c];
    atomicAdd(arow + c, acc);
}

// ------- r0/r2 transform: out[dst] += inv_deg * (agg @ Wr), then relu -------
__global__ __launch_bounds__(256) void smallT_kernel(
    const float* __restrict__ agg, const float* __restrict__ wr,
    const float* __restrict__ inv0, const float* __restrict__ inv2,
    float* __restrict__ outb)
{
    int row = blockIdx.x;            // 0..429
    int c = threadIdx.x;
    const float* a = agg + (size_t)row * D;
    const float* W = (row < NA) ? wr : (wr + 2 * DD);
    float scale = (row < NA) ? inv0[row] : inv2[row - NA];
    float acc = 0.f;
    #pragma unroll 8
    for (int k = 0; k < D; ++k) acc += a[k] * W[k * D + c];
    size_t o = (size_t)(NF + row) * D + c;
    float v = outb[o] + scale * acc;
    outb[o] = fmaxf(v, 0.f);
}

// ------- r1/r3 gather into flights: out[f] += inv*Σ y[src], then relu -------
__global__ __launch_bounds__(256) void r1r3_kernel(
    const float* __restrict__ y,
    const int* __restrict__ rp1, const int* __restrict__ csr1, const float* __restrict__ inv1,
    const int* __restrict__ rp3, const int* __restrict__ csr3, const float* __restrict__ inv3,
    float* __restrict__ outb)
{
    int c = threadIdx.x;
    int base = blockIdx.x * 8;
    for (int i = 0; i < 8; ++i) {
        int f = base + i;
        if (f >= NF) return;
        float s1 = 0.f;
        for (int a = rp1[f]; a < rp1[f + 1]; ++a)
            s1 += y[(size_t)csr1[a] * D + c];
        float s3 = 0.f;
        for (int a = rp3[f]; a < rp3[f + 1]; ++a)
            s3 += y[(size_t)(NA + csr3[a]) * D + c];
        size_t o = (size_t)f * D + c;
        float v = outb[o] + inv1[f] * s1 + inv3[f] * s3;
        outb[o] = fmaxf(v, 0.f);
    }
}

// ---------------- readout: out[f] = h[f] . W_out + b_out --------------------
__global__ __launch_bounds__(256) void readout_kernel(
    const float* __restrict__ h, const float* __restrict__ wout,
    const float* __restrict__ bout, float* __restrict__ out)
{
    int w = threadIdx.x >> 6, lane = threadIdx.x & 63;
    int row = blockIdx.x * 4 + w;
    if (row >= NF) return;
    float4 hv = *(const float4*)(h + (size_t)row * D + lane * 4);
    float4 wv = *(const float4*)(wout + lane * 4);
    float d = hv.x * wv.x + hv.y * wv.y + hv.z * wv.z + hv.w * wv.w;
    #pragma unroll
    for (int s = 32; s > 0; s >>= 1) d += __shfl_down(d, s);
    if (lane == 0) out[row] = d + bout[0];
}

extern "C" void kernel_launch(void* const* d_in, const int* in_sizes, int n_in,
                              void* d_out, int out_size, void* d_ws, size_t ws_size,
                              hipStream_t stream)
{
    const float* xf = (const float*)d_in[0];
    const float* xa = (const float*)d_in[1];
    const float* xc = (const float*)d_in[2];
    const float* Wf = (const float*)d_in[3];
    const float* bf = (const float*)d_in[4];
    const float* Wa = (const float*)d_in[5];
    const float* ba = (const float*)d_in[6];
    const float* Wc = (const float*)d_in[7];
    const float* bc = (const float*)d_in[8];
    const float* basis0 = (const float*)d_in[9];
    const float* comp0  = (const float*)d_in[10];
    const float* root0  = (const float*)d_in[11];
    const float* bias0  = (const float*)d_in[12];
    const float* basis1 = (const float*)d_in[13];
    const float* comp1  = (const float*)d_in[14];
    const float* root1  = (const float*)d_in[15];
    const float* bias1  = (const float*)d_in[16];
    const float* Wout = (const float*)d_in[17];
    const float* bout = (const float*)d_in[18];
    const int* src0 = (const int*)d_in[19];
    const int* dst0 = (const int*)d_in[20];
    const int* src1 = (const int*)d_in[21];
    const int* dst1 = (const int*)d_in[22];
    const int* src2 = (const int*)d_in[23];
    const int* dst2 = (const int*)d_in[24];
    const int* src3 = (const int*)d_in[25];
    const int* dst3 = (const int*)d_in[26];
    float* out = (float*)d_out;

    char* ws = (char*)d_ws;
    size_t off = 0;
    auto alloc = [&](size_t bytes) -> char* {
        char* p = ws + off;
        off = (off + bytes + 255) & ~(size_t)255;
        return p;
    };
    float* hbuf   = (float*)alloc((size_t)NN * D * 4);
    float* obuf   = (float*)alloc((size_t)NN * D * 4);
    float* wrbuf  = (float*)alloc((size_t)4 * DD * 4);
    float* ybuf   = (float*)alloc((size_t)(NA + NC) * D * 4);
    float* aggbuf = (float*)alloc((size_t)(NA + NC) * D * 4);
    int*   deg13  = (int*)  alloc((size_t)2 * NF * 4);
    int* deg1 = deg13; int* deg3 = deg13 + NF;
    float* inv1 = (float*)alloc((size_t)NF * 4);
    float* inv3 = (float*)alloc((size_t)NF * 4);
    float* inv0 = (float*)alloc((size_t)NA * 4);
    float* inv2 = (float*)alloc((size_t)NC * 4);
    int* rp0 = (int*)alloc((NA + 1) * 4);
    int* rp1 = (int*)alloc((size_t)(NF + 1) * 4);
    int* rp2 = (int*)alloc((NC + 1) * 4);
    int* rp3 = (int*)alloc((size_t)(NF + 1) * 4);
    int* cu1 = (int*)alloc((size_t)(NF + 1) * 4);
    int* cu3 = (int*)alloc((size_t)(NF + 1) * 4);
    int* csr0 = (int*)alloc((size_t)E * 4);
    int* csr1 = (int*)alloc((size_t)E * 4);
    int* csr2 = (int*)alloc((size_t)E * 4);
    int* csr3 = (int*)alloc((size_t)E * 4);
    int* bsum = (int*)alloc(256 * 4);
    int* bh0  = (int*)alloc((size_t)NSL * NA * 4);
    int* bh2  = (int*)alloc((size_t)NSL * NC * 4);
    (void)ws_size; (void)in_sizes; (void)n_in; (void)out_size;

    // ---- CSR build: r0/r2 via contention-free counting sort
    hist02_kernel<<<2 * NSL, 256, 0, stream>>>(dst0, dst2, bh0, bh2);
    scan02_kernel<<<1, 512, 0, stream>>>(bh0, bh2, rp0, rp2, inv0, inv2);
    fill02_kernel<<<2 * NSL, 256, 0, stream>>>(src0, dst0, src2, dst2, bh0, bh2, csr0, csr2);

    // ---- CSR build: r1/r3 via atomics (100K dsts, avg degree 2.5 — cheap)
    hipMemsetAsync(deg13, 0, (size_t)2 * NF * 4, stream);
    deg_count_kernel<<<(2 * E + 255) / 256, 256, 0, stream>>>(dst1, dst3, deg1, deg3);
    scanA_kernel<<<196, 1024, 0, stream>>>(deg1, deg3, bsum);
    scanB_kernel<<<1, 256, 0, stream>>>(bsum);
    scanC_kernel<<<196, 1024, 0, stream>>>(deg1, deg3, bsum, rp1, rp3, cu1, cu3, inv1, inv3);
    csr_fill13_kernel<<<(2 * E + 255) / 256, 256, 0, stream>>>(
        src1, dst1, src3, dst3, cu1, cu3, csr1, csr3);

    // ---- encoders
    encode_kernel<32, 8><<<NF / 8, 256, 0, stream>>>(xf, Wf, bf, hbuf, NF, 0);
    encode_kernel<16, 8><<<(NA + 7) / 8, 256, 0, stream>>>(xa, Wa, ba, hbuf, NA, NF);
    encode_kernel<8, 8><<<(NC + 7) / 8, 256, 0, stream>>>(xc, Wc, bc, hbuf, NC, NF + NA);

    // ---- RGCN layers (layer 1 skips r0/r2: airport/carrier outputs unused)
    auto layer = [&](const float* hin, float* hout,
                     const float* basis, const float* comp,
                     const float* root, const float* bias, bool do_small) {
        wr_kernel<<<4 * DD / 256, 256, 0, stream>>>(basis, comp, wrbuf);
        y_kernel<<<NA + NC, 256, 0, stream>>>(hin, wrbuf, ybuf);
        gemm_root<<<dim3((NN + 127) / 128, 2), 256, 0, stream>>>(hin, root, bias, hout);
        if (do_small) {
            hipMemsetAsync(aggbuf, 0, (size_t)(NA + NC) * D * 4, stream);
            agg_small_kernel<<<NA * 4 + NC * 64, 256, 0, stream>>>(
                hin, rp0, csr0, rp2, csr2, aggbuf);
            smallT_kernel<<<NA + NC, 256, 0, stream>>>(aggbuf, wrbuf, inv0, inv2, hout);
        }
        r1r3_kernel<<<NF / 8, 256, 0, stream>>>(
            ybuf, rp1, csr1, inv1, rp3, csr3, inv3, hout);
    };
    layer(hbuf, obuf, basis0, comp0, root0, bias0, true);
    layer(obuf, hbuf, basis1, comp1, root1, bias1, false);

    // ---- readout
    readout_kernel<<<NF / 4, 256, 0, stream>>>(hbuf, Wout, bout, out);
}

// Round 3
// 728.994 us; speedup vs baseline: 2.4729x; 1.0683x over previous
//
#include <hip/hip_runtime.h>
#include <cstdint>
#include <cstddef>

constexpr int NF = 100000;
constexpr int NA = 400;
constexpr int NC = 30;
constexpr int NN = NF + NA + NC;     // 100430
constexpr int D  = 256;
constexpr int DD = D * D;            // 65536
constexpr int E  = 250000;
constexpr int NSL = 128;             // slices for r0/r2 counting sort

// ---------------- per-type encoders: h = relu(x @ W + b) ----------------
template<int K, int ROWS>
__global__ __launch_bounds__(256) void encode_kernel(
    const float* __restrict__ x, const float* __restrict__ W,
    const float* __restrict__ b, float* __restrict__ h,
    int rows, int row_off)
{
    int c = threadIdx.x;
    int base = blockIdx.x * ROWS;
    float wcol[K];
    #pragma unroll
    for (int k = 0; k < K; ++k) wcol[k] = W[k * D + c];
    float bias = b[c];
    for (int i = 0; i < ROWS; ++i) {
        int row = base + i;
        if (row >= rows) return;
        const float* xr = x + (size_t)row * K;
        float acc = bias;
        #pragma unroll
        for (int k = 0; k < K; ++k) acc += xr[k] * wcol[k];
        h[(size_t)(row_off + row) * D + c] = fmaxf(acc, 0.f);
    }
}

// ---------------- r1/r3 degree count (low contention: 100K dsts) ----------
__global__ __launch_bounds__(256) void deg_count_kernel(
    const int* __restrict__ dst1, const int* __restrict__ dst3,
    int* __restrict__ deg1, int* __restrict__ deg3)
{
    int idx = blockIdx.x * 256 + threadIdx.x;
    if (idx >= 2 * E) return;
    if (idx < E) atomicAdd(&deg1[dst1[idx]], 1);
    else         atomicAdd(&deg3[dst3[idx - E]], 1);
}

// ---------------- r0/r2: per-slice LDS histograms (contention-free) --------
__global__ __launch_bounds__(256) void hist02_kernel(
    const int* __restrict__ dst0, const int* __restrict__ dst2,
    int* __restrict__ bh0, int* __restrict__ bh2)
{
    __shared__ int hist[NA];
    int b = blockIdx.x;                 // 0..2*NSL-1
    bool isR2 = (b >= NSL);
    int sl = isR2 ? b - NSL : b;
    const int* dst = isR2 ? dst2 : dst0;
    int nb = isR2 ? NC : NA;
    for (int i = threadIdx.x; i < nb; i += 256) hist[i] = 0;
    __syncthreads();
    int lo = (int)((long long)E * sl / NSL);
    int hi = (int)((long long)E * (sl + 1) / NSL);
    for (int e = lo + threadIdx.x; e < hi; e += 256)
        atomicAdd(&hist[dst[e]], 1);
    __syncthreads();
    int* bh = isR2 ? (bh2 + sl * NC) : (bh0 + sl * NA);
    for (int i = threadIdx.x; i < nb; i += 256) bh[i] = hist[i];
}

// -------- scan: per-bin over slices + cross-bin; emits rp/inv + abs offsets -
__global__ __launch_bounds__(512) void scan02_kernel(
    int* __restrict__ bh0, int* __restrict__ bh2,
    int* __restrict__ rp0, int* __restrict__ rp2,
    float* __restrict__ inv0, float* __restrict__ inv2)
{
    __shared__ int tot[512];
    __shared__ int exc[512];
    int t = threadIdx.x;
    int cnt = 0;
    if (t < NA) {
        int s = 0;
        for (int sl = 0; sl < NSL; ++sl) {
            int v = bh0[sl * NA + t]; bh0[sl * NA + t] = s; s += v;
        }
        cnt = s;
    } else if (t < NA + NC) {
        int bin = t - NA; int s = 0;
        for (int sl = 0; sl < NSL; ++sl) {
            int v = bh2[sl * NC + bin]; bh2[sl * NC + bin] = s; s += v;
        }
        cnt = s;
    }
    tot[t] = cnt;
    __syncthreads();
    for (int ofs = 1; ofs < 512; ofs <<= 1) {
        int v = (t >= ofs) ? tot[t - ofs] : 0;
        __syncthreads();
        tot[t] += v;
        __syncthreads();
    }
    int ex = tot[t] - cnt;              // exclusive over combined [r0 | r2]
    if (t < NA) {
        exc[t] = ex;
        rp0[t] = ex;
        inv0[t] = 1.0f / (float)(cnt > 1 ? cnt : 1);
        if (t == 0) { rp0[NA] = E; rp2[NC] = E; }
    } else if (t < NA + NC) {
        exc[t] = ex - E;                // r2 csr buffer is its own array
        rp2[t - NA] = ex - E;
        inv2[t - NA] = 1.0f / (float)(cnt > 1 ? cnt : 1);
    } else exc[t] = 0;
    __syncthreads();
    for (int idx = t; idx < NSL * NA; idx += 512) {
        int sl = idx / NA; int bin = idx - sl * NA;
        bh0[idx] += exc[bin];
    }
    for (int idx = t; idx < NSL * NC; idx += 512) {
        int sl = idx / NC; int bin = idx - sl * NC;
        bh2[idx] += exc[NA + bin];
    }
}

// ---------------- r0/r2 CSR fill with LDS cursors --------------------------
__global__ __launch_bounds__(256) void fill02_kernel(
    const int* __restrict__ src0, const int* __restrict__ dst0,
    const int* __restrict__ src2, const int* __restrict__ dst2,
    const int* __restrict__ bh0, const int* __restrict__ bh2,
    int* __restrict__ csr0, int* __restrict__ csr2)
{
    __shared__ int cur[NA];
    int b = blockIdx.x;
    bool isR2 = (b >= NSL);
    int sl = isR2 ? b - NSL : b;
    const int* src = isR2 ? src2 : src0;
    const int* dst = isR2 ? dst2 : dst0;
    const int* bh  = isR2 ? (bh2 + sl * NC) : (bh0 + sl * NA);
    int* csr       = isR2 ? csr2 : csr0;
    int nb = isR2 ? NC : NA;
    for (int i = threadIdx.x; i < nb; i += 256) cur[i] = bh[i];
    __syncthreads();
    int lo = (int)((long long)E * sl / NSL);
    int hi = (int)((long long)E * (sl + 1) / NSL);
    for (int e = lo + threadIdx.x; e < hi; e += 256) {
        int pos = atomicAdd(&cur[dst[e]], 1);
        csr[pos] = src[e];
    }
}

// ---------------- r1/r3 scan chain -----------------------------------------
__global__ __launch_bounds__(1024) void scanA_kernel(
    const int* __restrict__ deg1, const int* __restrict__ deg3, int* __restrict__ bsum)
{
    __shared__ int s[1024];
    int b = blockIdx.x;                    // 0..195
    bool isR3 = (b >= 98);
    const int* deg = isR3 ? deg3 : deg1;
    int chunk = isR3 ? b - 98 : b;
    int i = chunk * 1024 + threadIdx.x;
    int v = (i < NF) ? deg[i] : 0;
    s[threadIdx.x] = v;
    __syncthreads();
    for (int ofs = 512; ofs > 0; ofs >>= 1) {
        if ((int)threadIdx.x < ofs) s[threadIdx.x] += s[threadIdx.x + ofs];
        __syncthreads();
    }
    if (threadIdx.x == 0) bsum[(isR3 ? 128 : 0) + chunk] = s[0];
}

__global__ __launch_bounds__(256) void scanB_kernel(int* __restrict__ bsum)
{
    __shared__ int s[256];
    int t = threadIdx.x;
    int v = ((t & 127) < 98) ? bsum[t] : 0;
    s[t] = v;
    __syncthreads();
    for (int ofs = 1; ofs < 128; ofs <<= 1) {
        int a = ((t & 127) >= ofs) ? s[t - ofs] : 0;
        __syncthreads();
        s[t] += a;
        __syncthreads();
    }
    bsum[t] = s[t] - v;   // exclusive (segmented per 128-half)
}

__global__ __launch_bounds__(1024) void scanC_kernel(
    const int* __restrict__ deg1, const int* __restrict__ deg3,
    const int* __restrict__ bsum,
    int* __restrict__ rp1, int* __restrict__ rp3,
    int* __restrict__ cu1, int* __restrict__ cu3,
    float* __restrict__ inv1, float* __restrict__ inv3)
{
    __shared__ int s[1024];
    int b = blockIdx.x;                    // 0..195
    const int* deg; int* rp; int* cu; float* inv; int chunk; int prefix;
    if (b < 98) { deg = deg1; rp = rp1; cu = cu1; inv = inv1; chunk = b;      prefix = bsum[chunk]; }
    else        { deg = deg3; rp = rp3; cu = cu3; inv = inv3; chunk = b - 98; prefix = bsum[128 + chunk]; }
    int tid = threadIdx.x;
    int i = chunk * 1024 + tid;
    int v = (i < NF) ? deg[i] : 0;
    s[tid] = v;
    __syncthreads();
    for (int ofs = 1; ofs < 1024; ofs <<= 1) {
        int a = (tid >= ofs) ? s[tid - ofs] : 0;
        __syncthreads();
        s[tid] += a;
        __syncthreads();
    }
    int ex = prefix + s[tid] - v;
    if (i < NF) {
        rp[i] = ex;
        cu[i] = ex;
        inv[i] = 1.0f / (float)(v > 1 ? v : 1);
    }
    if (i == 0) rp[NF] = E;
}

__global__ __launch_bounds__(256) void csr_fill13_kernel(
    const int* __restrict__ src1, const int* __restrict__ dst1,
    const int* __restrict__ src3, const int* __restrict__ dst3,
    int* __restrict__ cu1, int* __restrict__ cu3,
    int* __restrict__ csr1, int* __restrict__ csr3)
{
    int idx = blockIdx.x * 256 + threadIdx.x;
    if (idx >= 2 * E) return;
    if (idx < E) {
        int pos = atomicAdd(&cu1[dst1[idx]], 1);
        csr1[pos] = src1[idx];
    } else {
        int e = idx - E;
        int pos = atomicAdd(&cu3[dst3[e]], 1);
        csr3[pos] = src3[e];
    }
}

// ------- y = h[src-type rows] @ Wr (Wr combined from basis on the fly) ------
__global__ __launch_bounds__(256) void y_kernel(
    const float* __restrict__ h, const float* __restrict__ basis,
    const float* __restrict__ comp, float* __restrict__ y)
{
    int row = blockIdx.x;            // 0..429  (airports then carriers)
    int c = threadIdx.x;
    const float* src = h + (size_t)(NF + row) * D;
    int rel = (row < NA) ? 1 : 3;
    float c0 = comp[rel * 3 + 0], c1 = comp[rel * 3 + 1], c2 = comp[rel * 3 + 2];
    float acc = 0.f;
    #pragma unroll 4
    for (int k = 0; k < D; ++k) {
        float w = c0 * basis[k * D + c] + c1 * basis[DD + k * D + c]
                + c2 * basis[2 * DD + k * D + c];
        acc += src[k] * w;
    }
    y[(size_t)row * D + c] = acc;
}

// ---- fused GEMM: C = A @ root + bias, + r1/r3 messages + relu (flights) ----
// MODE 0: write full rows to C (obuf); rows >= NF raw (smallT finishes them).
// MODE 1: rows are flights only; after relu, dot with W_out -> partial[2*NF].
template<int MODE>
__global__ __launch_bounds__(256) void gemm_fused(
    const float* __restrict__ A, const float* __restrict__ Bm,
    const float* __restrict__ bias, const float* __restrict__ y,
    const int* __restrict__ rp1, const int* __restrict__ csr1, const float* __restrict__ inv1,
    const int* __restrict__ rp3, const int* __restrict__ csr3, const float* __restrict__ inv3,
    const float* __restrict__ wout, float* __restrict__ C, int nrows)
{
    constexpr int BM = 128, BN = 128, BK = 16;
    __shared__ float As[BK][BM + 4];
    __shared__ float Bs[BK][BN + 4];
    const int row0 = blockIdx.x * BM;
    const int col0 = blockIdx.y * BN;
    const int t = threadIdx.x;
    const int tx = t & 15, ty = t >> 4;
    float acc[8][8] = {};
    const int arow = t >> 1;             // 0..127
    const int acol = (t & 1) * 8;        // 0 or 8
    int ar = row0 + arow; if (ar >= nrows) ar = nrows - 1;
    const float* Ap = A + (size_t)ar * D + acol;
    const float* Bp = Bm + (size_t)(t >> 4) * D + col0 + (t & 15) * 8;
    // prologue loads (tile 0)
    float4 a0 = *(const float4*)(Ap);
    float4 a1 = *(const float4*)(Ap + 4);
    float4 b0 = *(const float4*)(Bp);
    float4 b1 = *(const float4*)(Bp + 4);
    for (int k0 = 0; k0 < D; k0 += BK) {
        __syncthreads();
        As[acol + 0][arow] = a0.x; As[acol + 1][arow] = a0.y;
        As[acol + 2][arow] = a0.z; As[acol + 3][arow] = a0.w;
        As[acol + 4][arow] = a1.x; As[acol + 5][arow] = a1.y;
        As[acol + 6][arow] = a1.z; As[acol + 7][arow] = a1.w;
        *(float4*)(&Bs[t >> 4][(t & 15) * 8])     = b0;
        *(float4*)(&Bs[t >> 4][(t & 15) * 8 + 4]) = b1;
        __syncthreads();
        if (k0 + BK < D) {               // prefetch next tile under compute
            a0 = *(const float4*)(Ap + k0 + BK);
            a1 = *(const float4*)(Ap + k0 + BK + 4);
            b0 = *(const float4*)(Bp + (size_t)(k0 + BK) * D);
            b1 = *(const float4*)(Bp + (size_t)(k0 + BK) * D + 4);
        }
        #pragma unroll
        for (int k = 0; k < BK; ++k) {
            float4 x0 = *(const float4*)(&As[k][ty * 4]);
            float4 x1 = *(const float4*)(&As[k][ty * 4 + 64]);
            float4 y0 = *(const float4*)(&Bs[k][tx * 4]);
            float4 y1 = *(const float4*)(&Bs[k][tx * 4 + 64]);
            float a8[8] = {x0.x, x0.y, x0.z, x0.w, x1.x, x1.y, x1.z, x1.w};
            float b8[8] = {y0.x, y0.y, y0.z, y0.w, y1.x, y1.y, y1.z, y1.w};
            #pragma unroll
            for (int i = 0; i < 8; ++i)
                #pragma unroll
                for (int j = 0; j < 8; ++j)
                    acc[i][j] += a8[i] * b8[j];
        }
    }
    float4 bv0 = *(const float4*)(bias + col0 + tx * 4);
    float4 bv1 = *(const float4*)(bias + col0 + tx * 4 + 64);
    float bb[8] = {bv0.x, bv0.y, bv0.z, bv0.w, bv1.x, bv1.y, bv1.z, bv1.w};
    float w8[8];
    if (MODE == 1) {
        float4 w0 = *(const float4*)(wout + col0 + tx * 4);
        float4 w1 = *(const float4*)(wout + col0 + tx * 4 + 64);
        w8[0] = w0.x; w8[1] = w0.y; w8[2] = w0.z; w8[3] = w0.w;
        w8[4] = w1.x; w8[5] = w1.y; w8[6] = w1.z; w8[7] = w1.w;
    }
    for (int i = 0; i < 8; ++i) {
        int r = row0 + ty * 4 + (i & 3) + ((i & 4) ? 64 : 0);
        if (r >= nrows) continue;
        float v[8];
        #pragma unroll
        for (int j = 0; j < 8; ++j) v[j] = acc[i][j] + bb[j];
        if (MODE == 1 || r < NF) {
            // r1 messages (airport -> flight)
            float sv[8] = {0,0,0,0,0,0,0,0};
            for (int a2 = rp1[r]; a2 < rp1[r + 1]; ++a2) {
                const float* yr = y + (size_t)csr1[a2] * D + col0 + tx * 4;
                float4 u0 = *(const float4*)yr;
                float4 u1 = *(const float4*)(yr + 64);
                sv[0] += u0.x; sv[1] += u0.y; sv[2] += u0.z; sv[3] += u0.w;
                sv[4] += u1.x; sv[5] += u1.y; sv[6] += u1.z; sv[7] += u1.w;
            }
            float sc = inv1[r];
            #pragma unroll
            for (int j = 0; j < 8; ++j) v[j] += sc * sv[j];
            // r3 messages (carrier -> flight)
            float tv[8] = {0,0,0,0,0,0,0,0};
            for (int a2 = rp3[r]; a2 < rp3[r + 1]; ++a2) {
                const float* yr = y + (size_t)(NA + csr3[a2]) * D + col0 + tx * 4;
                float4 u0 = *(const float4*)yr;
                float4 u1 = *(const float4*)(yr + 64);
                tv[0] += u0.x; tv[1] += u0.y; tv[2] += u0.z; tv[3] += u0.w;
                tv[4] += u1.x; tv[5] += u1.y; tv[6] += u1.z; tv[7] += u1.w;
            }
            sc = inv3[r];
            #pragma unroll
            for (int j = 0; j < 8; ++j) v[j] = fmaxf(v[j] + sc * tv[j], 0.f);
        }
        if (MODE == 0) {
            float* Cp = C + (size_t)r * D + col0 + tx * 4;
            float4 o0 = {v[0], v[1], v[2], v[3]};
            float4 o1 = {v[4], v[5], v[6], v[7]};
            *(float4*)Cp = o0;
            *(float4*)(Cp + 64) = o1;
        } else {
            float pr = 0.f;
            #pragma unroll
            for (int j = 0; j < 8; ++j) pr += v[j] * w8[j];
            pr += __shfl_xor(pr, 1);
            pr += __shfl_xor(pr, 2);
            pr += __shfl_xor(pr, 4);
            pr += __shfl_xor(pr, 8);
            if (tx == 0) C[(size_t)blockIdx.y * NF + r] = pr;
        }
    }
}

// ---------------- r0/r2: agg[dst] += h[src] over CSR chunks -----------------
__global__ __launch_bounds__(256) void agg_small_kernel(
    const float* __restrict__ h,
    const int* __restrict__ rp0, const int* __restrict__ csr0,
    const int* __restrict__ rp2, const int* __restrict__ csr2,
    float* __restrict__ agg)
{
    int b = blockIdx.x;
    const int* rp; const int* csr; int dstn, chunk, nch; float* arow;
    if (b < NA * 4) { dstn = b >> 2; chunk = b & 3; nch = 4;  rp = rp0; csr = csr0; arow = agg + (size_t)dstn * D; }
    else { int bb = b - NA * 4; dstn = bb >> 6; chunk = bb & 63; nch = 64; rp = rp2; csr = csr2; arow = agg + (size_t)(NA + dstn) * D; }
    int s = rp[dstn], e = rp[dstn + 1];
    int cnt = e - s;
    int lo = s + (int)((long long)cnt * chunk / nch);
    int hi = s + (int)((long long)cnt * (chunk + 1) / nch);
    int c = threadIdx.x;
    float acc = 0.f;
    int p = lo;
    for (; p + 3 < hi; p += 4) {
        int s0 = csr[p], s1 = csr[p + 1], s2 = csr[p + 2], s3 = csr[p + 3];
        acc += h[(size_t)s0 * D + c] + h[(size_t)s1 * D + c]
             + h[(size_t)s2 * D + c] + h[(size_t)s3 * D + c];
    }
    for (; p < hi; ++p) acc += h[(size_t)csr[p] * D + c];
    atomicAdd(arow + c, acc);
}

// -- r0/r2 transform: out[dst] += inv_deg * (agg @ Wr), relu (basis on fly) --
__global__ __launch_bounds__(256) void smallT_kernel(
    const float* __restrict__ agg, const float* __restrict__ basis,
    const float* __restrict__ comp,
    const float* __restrict__ inv0, const float* __restrict__ inv2,
    float* __restrict__ outb)
{
    int row = blockIdx.x;            // 0..429
    int c = threadIdx.x;
    const float* a = agg + (size_t)row * D;
    int rel = (row < NA) ? 0 : 2;
    float c0 = comp[rel * 3 + 0], c1 = comp[rel * 3 + 1], c2 = comp[rel * 3 + 2];
    float scale = (row < NA) ? inv0[row] : inv2[row - NA];
    float acc = 0.f;
    #pragma unroll 4
    for (int k = 0; k < D; ++k) {
        float w = c0 * basis[k * D + c] + c1 * basis[DD + k * D + c]
                + c2 * basis[2 * DD + k * D + c];
        acc += a[k] * w;
    }
    size_t o = (size_t)(NF + row) * D + c;
    float v = outb[o] + scale * acc;
    outb[o] = fmaxf(v, 0.f);
}

// ---------------- combine readout partials ---------------------------------
__global__ __launch_bounds__(256) void combine_kernel(
    const float* __restrict__ part, const float* __restrict__ bout,
    float* __restrict__ out)
{
    int i = blockIdx.x * 256 + threadIdx.x;
    if (i < NF) out[i] = part[i] + part[NF + i] + bout[0];
}

extern "C" void kernel_launch(void* const* d_in, const int* in_sizes, int n_in,
                              void* d_out, int out_size, void* d_ws, size_t ws_size,
                              hipStream_t stream)
{
    const float* xf = (const float*)d_in[0];
    const float* xa = (const float*)d_in[1];
    const float* xc = (const float*)d_in[2];
    const float* Wf = (const float*)d_in[3];
    const float* bf = (const float*)d_in[4];
    const float* Wa = (const float*)d_in[5];
    const float* ba = (const float*)d_in[6];
    const float* Wc = (const float*)d_in[7];
    const float* bc = (const float*)d_in[8];
    const float* basis0 = (const float*)d_in[9];
    const float* comp0  = (const float*)d_in[10];
    const float* root0  = (const float*)d_in[11];
    const float* bias0  = (const float*)d_in[12];
    const float* basis1 = (const float*)d_in[13];
    const float* comp1  = (const float*)d_in[14];
    const float* root1  = (const float*)d_in[15];
    const float* bias1  = (const float*)d_in[16];
    const float* Wout = (const float*)d_in[17];
    const float* bout = (const float*)d_in[18];
    const int* src0 = (const int*)d_in[19];
    const int* dst0 = (const int*)d_in[20];
    const int* src1 = (const int*)d_in[21];
    const int* dst1 = (const int*)d_in[22];
    const int* src2 = (const int*)d_in[23];
    const int* dst2 = (const int*)d_in[24];
    const int* src3 = (const int*)d_in[25];
    const int* dst3 = (const int*)d_in[26];
    float* out = (float*)d_out;

    char* ws = (char*)d_ws;
    size_t off = 0;
    auto alloc = [&](size_t bytes) -> char* {
        char* p = ws + off;
        off = (off + bytes + 255) & ~(size_t)255;
        return p;
    };
    float* hbuf   = (float*)alloc((size_t)NN * D * 4);
    float* obuf   = (float*)alloc((size_t)NN * D * 4);
    float* ybuf   = (float*)alloc((size_t)(NA + NC) * D * 4);
    float* aggbuf = (float*)alloc((size_t)(NA + NC) * D * 4);
    float* part   = (float*)alloc((size_t)2 * NF * 4);
    int*   deg13  = (int*)  alloc((size_t)2 * NF * 4);
    int* deg1 = deg13; int* deg3 = deg13 + NF;
    float* inv1 = (float*)alloc((size_t)NF * 4);
    float* inv3 = (float*)alloc((size_t)NF * 4);
    float* inv0 = (float*)alloc((size_t)NA * 4);
    float* inv2 = (float*)alloc((size_t)NC * 4);
    int* rp0 = (int*)alloc((NA + 1) * 4);
    int* rp1 = (int*)alloc((size_t)(NF + 1) * 4);
    int* rp2 = (int*)alloc((NC + 1) * 4);
    int* rp3 = (int*)alloc((size_t)(NF + 1) * 4);
    int* cu1 = (int*)alloc((size_t)(NF + 1) * 4);
    int* cu3 = (int*)alloc((size_t)(NF + 1) * 4);
    int* csr0 = (int*)alloc((size_t)E * 4);
    int* csr1 = (int*)alloc((size_t)E * 4);
    int* csr2 = (int*)alloc((size_t)E * 4);
    int* csr3 = (int*)alloc((size_t)E * 4);
    int* bsum = (int*)alloc(256 * 4);
    int* bh0  = (int*)alloc((size_t)NSL * NA * 4);
    int* bh2  = (int*)alloc((size_t)NSL * NC * 4);
    (void)ws_size; (void)in_sizes; (void)n_in; (void)out_size;

    // ---- CSR build: r0/r2 via contention-free counting sort
    hist02_kernel<<<2 * NSL, 256, 0, stream>>>(dst0, dst2, bh0, bh2);
    scan02_kernel<<<1, 512, 0, stream>>>(bh0, bh2, rp0, rp2, inv0, inv2);
    fill02_kernel<<<2 * NSL, 256, 0, stream>>>(src0, dst0, src2, dst2, bh0, bh2, csr0, csr2);

    // ---- CSR build: r1/r3 via atomics (100K dsts, avg degree 2.5 — cheap)
    hipMemsetAsync(deg13, 0, (size_t)2 * NF * 4, stream);
    deg_count_kernel<<<(2 * E + 255) / 256, 256, 0, stream>>>(dst1, dst3, deg1, deg3);
    scanA_kernel<<<196, 1024, 0, stream>>>(deg1, deg3, bsum);
    scanB_kernel<<<1, 256, 0, stream>>>(bsum);
    scanC_kernel<<<196, 1024, 0, stream>>>(deg1, deg3, bsum, rp1, rp3, cu1, cu3, inv1, inv3);
    csr_fill13_kernel<<<(2 * E + 255) / 256, 256, 0, stream>>>(
        src1, dst1, src3, dst3, cu1, cu3, csr1, csr3);

    // ---- encoders
    encode_kernel<32, 8><<<NF / 8, 256, 0, stream>>>(xf, Wf, bf, hbuf, NF, 0);
    encode_kernel<16, 8><<<(NA + 7) / 8, 256, 0, stream>>>(xa, Wa, ba, hbuf, NA, NF);
    encode_kernel<8, 8><<<(NC + 7) / 8, 256, 0, stream>>>(xc, Wc, bc, hbuf, NC, NF + NA);

    // ---- layer 0: gemm + fused flight messages/relu; airports via agg path
    y_kernel<<<NA + NC, 256, 0, stream>>>(hbuf, basis0, comp0, ybuf);
    gemm_fused<0><<<dim3((NN + 127) / 128, 2), 256, 0, stream>>>(
        hbuf, root0, bias0, ybuf, rp1, csr1, inv1, rp3, csr3, inv3,
        nullptr, obuf, NN);
    hipMemsetAsync(aggbuf, 0, (size_t)(NA + NC) * D * 4, stream);
    agg_small_kernel<<<NA * 4 + NC * 64, 256, 0, stream>>>(
        hbuf, rp0, csr0, rp2, csr2, aggbuf);
    smallT_kernel<<<NA + NC, 256, 0, stream>>>(aggbuf, basis0, comp0, inv0, inv2, obuf);

    // ---- layer 1 (flights only) fused with readout; h2 never materialized
    y_kernel<<<NA + NC, 256, 0, stream>>>(obuf, basis1, comp1, ybuf);
    gemm_fused<1><<<dim3((NF + 127) / 128, 2), 256, 0, stream>>>(
        obuf, root1, bias1, ybuf, rp1, csr1, inv1, rp3, csr3, inv3,
        Wout, part, NF);
    combine_kernel<<<(NF + 255) / 256, 256, 0, stream>>>(part, bout, out);
}